// Round 1
// baseline (400.583 us; speedup 1.0000x reference)
//
#include <hip/hip_runtime.h>
#include <stdint.h>

typedef unsigned short u16;
typedef unsigned int u32;
typedef __bf16 bf16x8 __attribute__((ext_vector_type(8)));
typedef __bf16 bf16x4 __attribute__((ext_vector_type(4)));
typedef float f32x4 __attribute__((ext_vector_type(4)));

#define SEQ 2048

// async 16B global->LDS copy (wave-uniform LDS base + lane*16)
__device__ __forceinline__ void async16(const void* g, void* l) {
  __builtin_amdgcn_global_load_lds((const __attribute__((address_space(1))) void*)g,
                                   (__attribute__((address_space(3))) void*)l, 16, 0, 0);
}

// ---------------- prep kernels ----------------

__global__ void conv_x_kernel(const float* __restrict__ x, u16* __restrict__ xb) {
  int i = (blockIdx.x * 256 + threadIdx.x) * 4;
  float4 v = *(const float4*)(x + i);
  bf16x4 o;
  o[0] = (__bf16)v.x; o[1] = (__bf16)v.y; o[2] = (__bf16)v.z; o[3] = (__bf16)v.w;
  *(bf16x4*)(xb + i) = o;
}

// WeffT[p][n][k] = w_p[k][n] + 2*sum_r a_p[k][r]*u_p[r][n]   (p=3: w_o, no LoRA)
__global__ void prep_w_kernel(const float* __restrict__ wq, const float* __restrict__ wk,
                              const float* __restrict__ wv, const float* __restrict__ wo,
                              const float* __restrict__ aq, const float* __restrict__ ak,
                              const float* __restrict__ av,
                              const float* __restrict__ uq, const float* __restrict__ uk,
                              const float* __restrict__ uv,
                              u16* __restrict__ weffT) {
  const int p = blockIdx.y;
  const int tn0 = (blockIdx.x & 31) * 32, tk0 = (blockIdx.x >> 5) * 32;
  const float* w = (p == 0) ? wq : (p == 1) ? wk : (p == 2) ? wv : wo;
  const float* a = (p == 0) ? aq : (p == 1) ? ak : av;
  const float* u = (p == 0) ? uq : (p == 1) ? uk : uv;
  __shared__ float wt[32][33];
  __shared__ float at[32][8];
  __shared__ float ut[8][33];
  const int t = threadIdx.x;
  {
    int tk = t >> 3, tn4 = (t & 7) * 4;
    float4 v = *(const float4*)(w + (tk0 + tk) * 1024 + tn0 + tn4);
    wt[tk][tn4] = v.x; wt[tk][tn4 + 1] = v.y; wt[tk][tn4 + 2] = v.z; wt[tk][tn4 + 3] = v.w;
  }
  if (p < 3) {
    at[t >> 3][t & 7] = a[(tk0 + (t >> 3)) * 8 + (t & 7)];
    ut[t >> 5][t & 31] = u[(t >> 5) * 1024 + tn0 + (t & 31)];
  }
  __syncthreads();
  const int tn = t >> 3, tk4 = (t & 7) * 4;
  bf16x4 o;
#pragma unroll
  for (int jj = 0; jj < 4; ++jj) {
    int k = tk4 + jj;
    float val = wt[k][tn];
    if (p < 3) {
      float acc = 0.f;
#pragma unroll
      for (int r = 0; r < 8; ++r) acc += at[k][r] * ut[r][tn];
      val += 2.0f * acc;
    }
    o[jj] = (__bf16)val;
  }
  *(bf16x4*)(weffT + p * 1048576 + (tn0 + tn) * 1024 + tk0 + tk4) = o;
}

__global__ void prep_bias_kernel(const float* __restrict__ bq, const float* __restrict__ bk,
                                 const float* __restrict__ bv, float* __restrict__ bias_qkv) {
  int i = blockIdx.x * 256 + threadIdx.x;
  bias_qkv[i] = (i < 1024) ? bq[i] : (i < 2048) ? bk[i - 1024] : bv[i - 2048];
}

// ---------------- GEMM: OUT[v][u] = dot(U[u], V[v]) + bias[u] ----------------
// U: NU x K bf16 row-major (transposed weights), V: 8192 x K bf16 row-major.
// Block 128(u) x 128(v), BK=32, 4 waves in 2x2, wave tile 64x64 (4x4 MFMAs).

template <bool BF16_OUT>
__global__ __launch_bounds__(256, 2)
void gemm_tt(const u16* __restrict__ U, const u16* __restrict__ V, void* __restrict__ OUT,
             const float* __restrict__ bias, const int NU, const int K) {
  __shared__ __align__(16) char smU[8192];
  __shared__ __align__(16) char smV[8192];
  const int t = threadIdx.x;
  const int lane = t & 63, ln = lane & 15, g = lane >> 4, w = t >> 6;
  const int u0 = blockIdx.x * 128, v0 = blockIdx.y * 128;
  const int wu = (w & 1) * 64, wv = (w >> 1) * 64;
  f32x4 acc[4][4] = {};
  for (int k0 = 0; k0 < K; k0 += 32) {
    __syncthreads();
#pragma unroll
    for (int half = 0; half < 2; ++half) {
      int c = half * 256 + t;
      int s = c >> 2, q = c & 3;
      int ldsoff = (half * 256 + (t & 192)) * 16;
      async16(U + (u0 + s) * K + k0 + q * 8, smU + ldsoff);
      async16(V + (v0 + s) * K + k0 + q * 8, smV + ldsoff);
    }
    __syncthreads();
    bf16x8 af[4], bf[4];
#pragma unroll
    for (int mt = 0; mt < 4; ++mt) af[mt] = *(const bf16x8*)(smU + (wu + mt * 16 + ln) * 64 + g * 16);
#pragma unroll
    for (int nt = 0; nt < 4; ++nt) bf[nt] = *(const bf16x8*)(smV + (wv + nt * 16 + ln) * 64 + g * 16);
#pragma unroll
    for (int mt = 0; mt < 4; ++mt)
#pragma unroll
      for (int nt = 0; nt < 4; ++nt)
        acc[mt][nt] = __builtin_amdgcn_mfma_f32_16x16x32_bf16(af[mt], bf[nt], acc[mt][nt], 0, 0, 0);
  }
  // epilogue: C row = u (4 consecutive regs), col = v
#pragma unroll
  for (int mt = 0; mt < 4; ++mt) {
    const int u = u0 + wu + mt * 16 + g * 4;
    const float4 bs = *(const float4*)(bias + u);
#pragma unroll
    for (int nt = 0; nt < 4; ++nt) {
      const int v = v0 + wv + nt * 16 + ln;
      f32x4 a = acc[mt][nt];
      a[0] += bs.x; a[1] += bs.y; a[2] += bs.z; a[3] += bs.w;
      if (BF16_OUT) {
        bf16x4 o;
        o[0] = (__bf16)a[0]; o[1] = (__bf16)a[1]; o[2] = (__bf16)a[2]; o[3] = (__bf16)a[3];
        *(bf16x4*)((u16*)OUT + (size_t)v * NU + u) = o;
      } else {
        *(float4*)((float*)OUT + (size_t)v * NU + u) = make_float4(a[0], a[1], a[2], a[3]);
      }
    }
  }
}

// ---------------- flash attention ----------------
// One block per (b, h, 128-row q-tile). Computes S^T = K @ Q^T so P lands with
// rows = s' (reg-contiguous -> packed b64 LDS writes) and softmax stats are
// per-lane-column, matching the O^T = V^T @ P^T phase directly.

__global__ __launch_bounds__(256, 2)
void attn_kernel(const u16* __restrict__ qkv, u16* __restrict__ attn_o) {
  __shared__ __align__(16) char smQ[16384];   // [2 kk][128 q][32 k]
  __shared__ __align__(16) char smK[16384];   // [2 kk][128 s'][32 k]
  __shared__ __align__(16) char smVt[16384];  // [4 kk][64 d][32 s']
  __shared__ __align__(16) char smP[32768];   // per wave 8KB: [4 kk][32 q][32 s']
  const int t = threadIdx.x;
  const int lane = t & 63, ln = lane & 15, g = lane >> 4, w = t >> 6;
  const int qt = blockIdx.x, h = blockIdx.y, b = blockIdx.z;
  const int q0 = qt * 128;
  const int base_bh = b * SEQ * 3072 + h * 64;
  // stage Q tile (persists across the whole kernel)
#pragma unroll
  for (int half = 0; half < 4; ++half) {
    int c = half * 256 + t;
    int kk = c >> 9, s = (c >> 2) & 127, q2 = c & 3;
    async16(qkv + base_bh + (q0 + s) * 3072 + kk * 32 + q2 * 8,
            smQ + (half * 256 + (t & 192)) * 16);
  }
  float m_run[2] = {-1e30f, -1e30f}, l_run[2] = {0.f, 0.f};
  f32x4 accO[4][2] = {};
  for (int kt = 0; kt < 16; ++kt) {
    const int kbase = base_bh + 1024 + kt * 128 * 3072;
    const int vbase = base_bh + 2048 + kt * 128 * 3072;
    __syncthreads();  // prev iter done with smK/smVt/smP; Q loads drained on iter 0
    // stage K tile
#pragma unroll
    for (int half = 0; half < 4; ++half) {
      int c = half * 256 + t;
      int kk = c >> 9, s = (c >> 2) & 127, q2 = c & 3;
      async16(qkv + kbase + s * 3072 + kk * 32 + q2 * 8,
              smK + (half * 256 + (t & 192)) * 16);
    }
    // stage V transposed: pairs of rows -> packed b32 LDS writes
    uint4 va[2], vb[2];
#pragma unroll
    for (int i = 0; i < 2; ++i) {
      int p = i * 256 + t, dq = p & 7, sp = p >> 3;
      const u16* gv = qkv + vbase + sp * 2 * 3072 + dq * 8;
      va[i] = *(const uint4*)gv;
      vb[i] = *(const uint4*)(gv + 3072);
    }
#pragma unroll
    for (int i = 0; i < 2; ++i) {
      int p = i * 256 + t, dq = p & 7, sp = p >> 3;
      char* dst = smVt + (sp >> 4) * 4096 + (sp & 15) * 4;
      u32 wa[4] = {va[i].x, va[i].y, va[i].z, va[i].w};
      u32 wb2[4] = {vb[i].x, vb[i].y, vb[i].z, vb[i].w};
#pragma unroll
      for (int jj = 0; jj < 4; ++jj) {
        u32 lo = (wa[jj] & 0xffffu) | (wb2[jj] << 16);
        u32 hi = (wa[jj] >> 16) | (wb2[jj] & 0xffff0000u);
        *(u32*)(dst + (dq * 8 + 2 * jj) * 64) = lo;
        *(u32*)(dst + (dq * 8 + 2 * jj + 1) * 64) = hi;
      }
    }
    __syncthreads();
    // S^T = K @ Q^T : rows s' (8 m-tiles), cols = this wave's 32 q (2 n-tiles)
    f32x4 st[8][2] = {};
#pragma unroll
    for (int kk = 0; kk < 2; ++kk) {
      bf16x8 qf0 = *(const bf16x8*)(smQ + kk * 8192 + (w * 32 + ln) * 64 + g * 16);
      bf16x8 qf1 = *(const bf16x8*)(smQ + kk * 8192 + (w * 32 + 16 + ln) * 64 + g * 16);
#pragma unroll
      for (int mt = 0; mt < 8; ++mt) {
        bf16x8 kf = *(const bf16x8*)(smK + kk * 8192 + (mt * 16 + ln) * 64 + g * 16);
        st[mt][0] = __builtin_amdgcn_mfma_f32_16x16x32_bf16(kf, qf0, st[mt][0], 0, 0, 0);
        st[mt][1] = __builtin_amdgcn_mfma_f32_16x16x32_bf16(kf, qf1, st[mt][1], 0, 0, 0);
      }
    }
    // online softmax (scale 1/8 folded into exp) + P write (b64-packed)
#pragma unroll
    for (int nt = 0; nt < 2; ++nt) {
      float tmax = -1e30f;
#pragma unroll
      for (int mt = 0; mt < 8; ++mt)
#pragma unroll
        for (int r = 0; r < 4; ++r) tmax = fmaxf(tmax, st[mt][nt][r]);
      tmax = fmaxf(tmax, __shfl_xor(tmax, 16));
      tmax = fmaxf(tmax, __shfl_xor(tmax, 32));
      float mnew = fmaxf(m_run[nt], tmax);
      float alpha = __expf((m_run[nt] - mnew) * 0.125f);
      m_run[nt] = mnew;
      float ps = 0.f;
#pragma unroll
      for (int mt = 0; mt < 8; ++mt) {
        bf16x4 pk;
#pragma unroll
        for (int r = 0; r < 4; ++r) {
          float pv = __expf((st[mt][nt][r] - mnew) * 0.125f);
          ps += pv;
          pk[r] = (__bf16)pv;
        }
        *(bf16x4*)(smP + w * 8192 + (mt >> 1) * 2048 + (nt * 16 + ln) * 64 +
                   ((mt & 1) * 16 + g * 4) * 2) = pk;
      }
      ps += __shfl_xor(ps, 16);
      ps += __shfl_xor(ps, 32);
      l_run[nt] = l_run[nt] * alpha + ps;
#pragma unroll
      for (int ot = 0; ot < 4; ++ot)
#pragma unroll
        for (int r = 0; r < 4; ++r) accO[ot][nt][r] *= alpha;
    }
    __syncthreads();
    // O^T += V^T @ P^T : rows d (4 m-tiles), cols = wave's 32 q (2 n-tiles)
#pragma unroll
    for (int kk = 0; kk < 4; ++kk) {
      bf16x8 pf0 = *(const bf16x8*)(smP + w * 8192 + kk * 2048 + ln * 64 + g * 16);
      bf16x8 pf1 = *(const bf16x8*)(smP + w * 8192 + kk * 2048 + (16 + ln) * 64 + g * 16);
#pragma unroll
      for (int ot = 0; ot < 4; ++ot) {
        bf16x8 vf = *(const bf16x8*)(smVt + kk * 4096 + (ot * 16 + ln) * 64 + g * 16);
        accO[ot][0] = __builtin_amdgcn_mfma_f32_16x16x32_bf16(vf, pf0, accO[ot][0], 0, 0, 0);
        accO[ot][1] = __builtin_amdgcn_mfma_f32_16x16x32_bf16(vf, pf1, accO[ot][1], 0, 0, 0);
      }
    }
  }
  // epilogue: O^T col = token (per-lane), rows d reg-contiguous -> 8B stores
#pragma unroll
  for (int nt = 0; nt < 2; ++nt) {
    const float il = 1.0f / l_run[nt];
    const int s = q0 + w * 32 + nt * 16 + ln;
#pragma unroll
    for (int ot = 0; ot < 4; ++ot) {
      bf16x4 o;
#pragma unroll
      for (int r = 0; r < 4; ++r) o[r] = (__bf16)(accO[ot][nt][r] * il);
      *(bf16x4*)(attn_o + (b * SEQ + s) * 1024 + h * 64 + ot * 16 + g * 4) = o;
    }
  }
}

// ---------------- launcher ----------------

extern "C" void kernel_launch(void* const* d_in, const int* in_sizes, int n_in,
                              void* d_out, int out_size, void* d_ws, size_t ws_size,
                              hipStream_t stream) {
  const float* x  = (const float*)d_in[0];
  const float* wq = (const float*)d_in[1];
  const float* bq = (const float*)d_in[2];
  const float* wk = (const float*)d_in[3];
  const float* bk = (const float*)d_in[4];
  const float* wv = (const float*)d_in[5];
  const float* bv = (const float*)d_in[6];
  const float* wo = (const float*)d_in[7];
  const float* bo = (const float*)d_in[8];
  const float* aq = (const float*)d_in[9];
  const float* uq = (const float*)d_in[10];
  const float* ak = (const float*)d_in[11];
  const float* uk = (const float*)d_in[12];
  const float* av = (const float*)d_in[13];
  const float* uv = (const float*)d_in[14];

  char* ws = (char*)d_ws;
  // xb dead after the QKV GEMM; attn_o reuses its 16 MB.
  u16* xb       = (u16*)(ws);                      // 16 MB  [0,16M)
  u16* attn_o   = (u16*)(ws);                      // 16 MB  (reuse)
  u16* qkv      = (u16*)(ws + (16u << 20));        // 48 MB  [16M,64M)
  u16* weffT    = (u16*)(ws + (64u << 20));        // 8 MB   [64M,72M)
  float* biasq  = (float*)(ws + (72u << 20));      // 12 KB

  conv_x_kernel<<<dim3(8192), dim3(256), 0, stream>>>(x, xb);
  prep_w_kernel<<<dim3(1024, 4), dim3(256), 0, stream>>>(wq, wk, wv, wo, aq, ak, av, uq, uk, uv, weffT);
  prep_bias_kernel<<<dim3(12), dim3(256), 0, stream>>>(bq, bk, bv, biasq);
  gemm_tt<true><<<dim3(24, 64), dim3(256), 0, stream>>>(weffT, xb, (void*)qkv, biasq, 3072, 1024);
  attn_kernel<<<dim3(16, 16, 4), dim3(256), 0, stream>>>(qkv, attn_o);
  gemm_tt<false><<<dim3(8, 64), dim3(256), 0, stream>>>(weffT + 3u * 1048576u, attn_o, d_out, bo, 1024, 1024);
}

// Round 2
// 360.383 us; speedup vs baseline: 1.1115x; 1.1115x over previous
//
#include <hip/hip_runtime.h>
#include <stdint.h>

typedef unsigned short u16;
typedef unsigned int u32;
typedef __bf16 bf16x8 __attribute__((ext_vector_type(8)));
typedef __bf16 bf16x4 __attribute__((ext_vector_type(4)));
typedef float f32x4 __attribute__((ext_vector_type(4)));

#define SEQ 2048

// async 16B global->LDS copy (wave-uniform LDS base + lane*16)
__device__ __forceinline__ void async16(const void* g, void* l) {
  __builtin_amdgcn_global_load_lds((const __attribute__((address_space(1))) void*)g,
                                   (__attribute__((address_space(3))) void*)l, 16, 0, 0);
}

// ---------------- prep kernels ----------------

__global__ void conv_x_kernel(const float* __restrict__ x, u16* __restrict__ xb) {
  int i = (blockIdx.x * 256 + threadIdx.x) * 4;
  float4 v = *(const float4*)(x + i);
  bf16x4 o;
  o[0] = (__bf16)v.x; o[1] = (__bf16)v.y; o[2] = (__bf16)v.z; o[3] = (__bf16)v.w;
  *(bf16x4*)(xb + i) = o;
}

// WeffT[p][n][k] = w_p[k][n] + 2*sum_r a_p[k][r]*u_p[r][n]   (p=3: w_o, no LoRA)
__global__ void prep_w_kernel(const float* __restrict__ wq, const float* __restrict__ wk,
                              const float* __restrict__ wv, const float* __restrict__ wo,
                              const float* __restrict__ aq, const float* __restrict__ ak,
                              const float* __restrict__ av,
                              const float* __restrict__ uq, const float* __restrict__ uk,
                              const float* __restrict__ uv,
                              u16* __restrict__ weffT) {
  const int p = blockIdx.y;
  const int tn0 = (blockIdx.x & 31) * 32, tk0 = (blockIdx.x >> 5) * 32;
  const float* w = (p == 0) ? wq : (p == 1) ? wk : (p == 2) ? wv : wo;
  const float* a = (p == 0) ? aq : (p == 1) ? ak : av;
  const float* u = (p == 0) ? uq : (p == 1) ? uk : uv;
  __shared__ float wt[32][33];
  __shared__ float at[32][8];
  __shared__ float ut[8][33];
  const int t = threadIdx.x;
  {
    int tk = t >> 3, tn4 = (t & 7) * 4;
    float4 v = *(const float4*)(w + (tk0 + tk) * 1024 + tn0 + tn4);
    wt[tk][tn4] = v.x; wt[tk][tn4 + 1] = v.y; wt[tk][tn4 + 2] = v.z; wt[tk][tn4 + 3] = v.w;
  }
  if (p < 3) {
    at[t >> 3][t & 7] = a[(tk0 + (t >> 3)) * 8 + (t & 7)];
    ut[t >> 5][t & 31] = u[(t >> 5) * 1024 + tn0 + (t & 31)];
  }
  __syncthreads();
  const int tn = t >> 3, tk4 = (t & 7) * 4;
  bf16x4 o;
#pragma unroll
  for (int jj = 0; jj < 4; ++jj) {
    int k = tk4 + jj;
    float val = wt[k][tn];
    if (p < 3) {
      float acc = 0.f;
#pragma unroll
      for (int r = 0; r < 8; ++r) acc += at[k][r] * ut[r][tn];
      val += 2.0f * acc;
    }
    o[jj] = (__bf16)val;
  }
  *(bf16x4*)(weffT + p * 1048576 + (tn0 + tn) * 1024 + tk0 + tk4) = o;
}

__global__ void prep_bias_kernel(const float* __restrict__ bq, const float* __restrict__ bk,
                                 const float* __restrict__ bv, float* __restrict__ bias_qkv) {
  int i = blockIdx.x * 256 + threadIdx.x;
  bias_qkv[i] = (i < 1024) ? bq[i] : (i < 2048) ? bk[i - 1024] : bv[i - 2048];
}

// ---------------- GEMM: OUT[v][u] = dot(U[u], V[v]) + bias[u] ----------------
// Block 128(u) x 128(v), BK=32, 4 waves 2x2, wave tile 64x64 (4x4 MFMAs).
// LDS rows 64B (4 x 16B chunks), XOR-swizzled: chunk c of row r at c^(r&3).

template <bool BF16_OUT>
__global__ __launch_bounds__(256, 2)
void gemm_tt(const u16* __restrict__ U, const u16* __restrict__ V, void* __restrict__ OUT,
             const float* __restrict__ bias, const int NU, const int K) {
  __shared__ __align__(16) char smU[8192];
  __shared__ __align__(16) char smV[8192];
  const int t = threadIdx.x;
  const int lane = t & 63, ln = lane & 15, g = lane >> 4, w = t >> 6;
  const int u0 = blockIdx.x * 128, v0 = blockIdx.y * 128;
  const int wu = (w & 1) * 64, wv = (w >> 1) * 64;
  f32x4 acc[4][4] = {};
  for (int k0 = 0; k0 < K; k0 += 32) {
    __syncthreads();
#pragma unroll
    for (int half = 0; half < 2; ++half) {
      int p = half * 256 + t;
      int s = p >> 2, cp = p & 3;
      int c = cp ^ (s & 3);             // logical k-chunk for swizzled placement
      int ldsoff = (half * 256 + (t & 192)) * 16;
      async16(U + (u0 + s) * K + k0 + c * 8, smU + ldsoff);
      async16(V + (v0 + s) * K + k0 + c * 8, smV + ldsoff);
    }
    __syncthreads();
    bf16x8 af[4], bf[4];
#pragma unroll
    for (int mt = 0; mt < 4; ++mt)
      af[mt] = *(const bf16x8*)(smU + (wu + mt * 16 + ln) * 64 + ((g ^ (ln & 3)) * 16));
#pragma unroll
    for (int nt = 0; nt < 4; ++nt)
      bf[nt] = *(const bf16x8*)(smV + (wv + nt * 16 + ln) * 64 + ((g ^ (ln & 3)) * 16));
#pragma unroll
    for (int mt = 0; mt < 4; ++mt)
#pragma unroll
      for (int nt = 0; nt < 4; ++nt)
        acc[mt][nt] = __builtin_amdgcn_mfma_f32_16x16x32_bf16(af[mt], bf[nt], acc[mt][nt], 0, 0, 0);
  }
#pragma unroll
  for (int mt = 0; mt < 4; ++mt) {
    const int u = u0 + wu + mt * 16 + g * 4;
    const float4 bs = *(const float4*)(bias + u);
#pragma unroll
    for (int nt = 0; nt < 4; ++nt) {
      const int v = v0 + wv + nt * 16 + ln;
      f32x4 a = acc[mt][nt];
      a[0] += bs.x; a[1] += bs.y; a[2] += bs.z; a[3] += bs.w;
      if (BF16_OUT) {
        bf16x4 o;
        o[0] = (__bf16)a[0]; o[1] = (__bf16)a[1]; o[2] = (__bf16)a[2]; o[3] = (__bf16)a[3];
        *(bf16x4*)((u16*)OUT + (size_t)v * NU + u) = o;
      } else {
        *(float4*)((float*)OUT + (size_t)v * NU + u) = make_float4(a[0], a[1], a[2], a[3]);
      }
    }
  }
}

// ---------------- flash attention v2 ----------------
// Block = (h, qt, b), 128 q, 4 waves x 32 q. Q frags in registers.
// smK  [128 s'][128B, 8 chunks swz ^(r&7)]     (async16-staged)
// smVt [64 d][256B, 16 chunks swz ^((d&15)^(d>>3))] (manual transposed staging)
// smP  per wave [32 q][64B, 4 chunks swz ^(q&3)]    (wave-private, no barrier)

__global__ __launch_bounds__(256, 2)
void attn_kernel(const u16* __restrict__ qkv, u16* __restrict__ attn_o) {
  __shared__ __align__(16) char smK[16384];
  __shared__ __align__(16) char smVt[16384];
  __shared__ __align__(16) char smP[8192];
  const int t = threadIdx.x;
  const int lane = t & 63, ln = lane & 15, g = lane >> 4, w = t >> 6;
  const int h = blockIdx.x, qt = blockIdx.y, b = blockIdx.z;
  const int q0 = qt * 128;
  const int base_bh = b * SEQ * 3072 + h * 64;

  // Q fragments in registers: (kk, nt): q = q0 + w*32 + nt*16 + ln, k = kk*32 + g*8
  bf16x8 qf[2][2];
#pragma unroll
  for (int kk = 0; kk < 2; ++kk)
#pragma unroll
    for (int nt = 0; nt < 2; ++nt)
      qf[kk][nt] = *(const bf16x8*)(qkv + base_bh + (q0 + w * 32 + nt * 16 + ln) * 3072 +
                                    kk * 32 + g * 8);

  float m_run[2] = {-1e30f, -1e30f}, l_run[2] = {0.f, 0.f};
  f32x4 accO[4][2] = {};

  for (int kt = 0; kt < 16; ++kt) {
    const int kbase = base_bh + 1024 + kt * 128 * 3072;
    const int vbase = base_bh + 2048 + kt * 128 * 3072;
    __syncthreads();  // previous iteration done with smK/smVt/smP
    // stage K via async16, swizzled source: position p -> row p>>3, chunk (p&7)^(row&7)
#pragma unroll
    for (int i = 0; i < 4; ++i) {
      int p = i * 256 + t;
      int row = p >> 3, cp = p & 7;
      int c = cp ^ (row & 7);
      async16(qkv + kbase + row * 3072 + c * 8, smK + (i * 256 + (t & 192)) * 16);
    }
    // stage V transposed (manual, swizzled): pair-pack s' rows into u32 writes
#pragma unroll
    for (int i = 0; i < 2; ++i) {
      int sp = i * 32 + (t >> 3);        // s'-pair index 0..63
      int dq = t & 7;
      const u16* gv = qkv + vbase + sp * 2 * 3072 + dq * 8;
      uint4 va = *(const uint4*)gv;
      uint4 vb = *(const uint4*)(gv + 3072);
      u32 wa[4] = {va.x, va.y, va.z, va.w};
      u32 wb[4] = {vb.x, vb.y, vb.z, vb.w};
      int chunk = sp >> 2, sb = (sp & 3) * 4;
#pragma unroll
      for (int jj = 0; jj < 4; ++jj) {
        int d0 = dq * 8 + 2 * jj;
        u32 lo = (wa[jj] & 0xffffu) | (wb[jj] << 16);
        u32 hi = (wa[jj] >> 16) | (wb[jj] & 0xffff0000u);
        int k0d = (d0 & 15) ^ (d0 >> 3);
        int k1d = ((d0 + 1) & 15) ^ ((d0 + 1) >> 3);
        *(u32*)(smVt + d0 * 256 + ((chunk ^ k0d) & 15) * 16 + sb) = lo;
        *(u32*)(smVt + (d0 + 1) * 256 + ((chunk ^ k1d) & 15) * 16 + sb) = hi;
      }
    }
    __syncthreads();
    // S^T = K @ Q^T : rows s' (8 m-tiles), cols = wave's 32 q (2 n-tiles)
    f32x4 st[8][2] = {};
#pragma unroll
    for (int kk = 0; kk < 2; ++kk) {
#pragma unroll
      for (int mt = 0; mt < 8; ++mt) {
        int row = mt * 16 + ln;
        bf16x8 kf = *(const bf16x8*)(smK + row * 128 + (((4 * kk + g) ^ (ln & 7)) * 16));
        st[mt][0] = __builtin_amdgcn_mfma_f32_16x16x32_bf16(kf, qf[kk][0], st[mt][0], 0, 0, 0);
        st[mt][1] = __builtin_amdgcn_mfma_f32_16x16x32_bf16(kf, qf[kk][1], st[mt][1], 0, 0, 0);
      }
    }
    // online softmax (scale 1/8 folded into exp); st overwritten with exp'ed P (f32)
#pragma unroll
    for (int nt = 0; nt < 2; ++nt) {
      float tmax = -1e30f;
#pragma unroll
      for (int mt = 0; mt < 8; ++mt)
#pragma unroll
        for (int r = 0; r < 4; ++r) tmax = fmaxf(tmax, st[mt][nt][r]);
      tmax = fmaxf(tmax, __shfl_xor(tmax, 16));
      tmax = fmaxf(tmax, __shfl_xor(tmax, 32));
      float mnew = fmaxf(m_run[nt], tmax);
      float al = __expf((m_run[nt] - mnew) * 0.125f);
      m_run[nt] = mnew;
      float ps = 0.f;
#pragma unroll
      for (int mt = 0; mt < 8; ++mt)
#pragma unroll
        for (int r = 0; r < 4; ++r) {
          float pv = __expf((st[mt][nt][r] - mnew) * 0.125f);
          ps += pv;
          st[mt][nt][r] = pv;
        }
      ps += __shfl_xor(ps, 16);
      ps += __shfl_xor(ps, 32);
      l_run[nt] = l_run[nt] * al + ps;
#pragma unroll
      for (int ot = 0; ot < 4; ++ot)
#pragma unroll
        for (int r = 0; r < 4; ++r) accO[ot][nt][r] *= al;
    }
    // PV in 4 chunks of 32 s' through wave-private smP (write then read, no barrier)
    char* pw = smP + w * 2048;
#pragma unroll
    for (int kk = 0; kk < 4; ++kk) {
#pragma unroll
      for (int mt2 = 0; mt2 < 2; ++mt2) {
#pragma unroll
        for (int nt = 0; nt < 2; ++nt) {
          f32x4 sv = st[kk * 2 + mt2][nt];
          bf16x4 pk;
#pragma unroll
          for (int r = 0; r < 4; ++r) pk[r] = (__bf16)sv[r];
          int q = nt * 16 + ln;
          int c = 2 * mt2 + (g >> 1);
          *(bf16x4*)(pw + q * 64 + ((c ^ (q & 3)) * 16) + (g & 1) * 8) = pk;
        }
      }
      bf16x8 pf0 = *(const bf16x8*)(pw + ln * 64 + ((g ^ (ln & 3)) * 16));
      bf16x8 pf1 = *(const bf16x8*)(pw + (16 + ln) * 64 + ((g ^ (ln & 3)) * 16));
#pragma unroll
      for (int ot = 0; ot < 4; ++ot) {
        int row = ot * 16 + ln;
        int key = (row & 15) ^ (row >> 3);
        bf16x8 vf = *(const bf16x8*)(smVt + row * 256 + (((4 * kk + g) ^ key) & 15) * 16);
        accO[ot][0] = __builtin_amdgcn_mfma_f32_16x16x32_bf16(vf, pf0, accO[ot][0], 0, 0, 0);
        accO[ot][1] = __builtin_amdgcn_mfma_f32_16x16x32_bf16(vf, pf1, accO[ot][1], 0, 0, 0);
      }
    }
  }
  // epilogue: O^T col = token (per-lane), rows d reg-contiguous -> 8B stores
#pragma unroll
  for (int nt = 0; nt < 2; ++nt) {
    const float il = 1.0f / l_run[nt];
    const int s = q0 + w * 32 + nt * 16 + ln;
#pragma unroll
    for (int ot = 0; ot < 4; ++ot) {
      bf16x4 o;
#pragma unroll
      for (int r = 0; r < 4; ++r) o[r] = (__bf16)(accO[ot][nt][r] * il);
      *(bf16x4*)(attn_o + (b * SEQ + s) * 1024 + h * 64 + ot * 16 + g * 4) = o;
    }
  }
}

// ---------------- launcher ----------------

extern "C" void kernel_launch(void* const* d_in, const int* in_sizes, int n_in,
                              void* d_out, int out_size, void* d_ws, size_t ws_size,
                              hipStream_t stream) {
  const float* x  = (const float*)d_in[0];
  const float* wq = (const float*)d_in[1];
  const float* bq = (const float*)d_in[2];
  const float* wk = (const float*)d_in[3];
  const float* bk = (const float*)d_in[4];
  const float* wv = (const float*)d_in[5];
  const float* bv = (const float*)d_in[6];
  const float* wo = (const float*)d_in[7];
  const float* bo = (const float*)d_in[8];
  const float* aq = (const float*)d_in[9];
  const float* uq = (const float*)d_in[10];
  const float* ak = (const float*)d_in[11];
  const float* uk = (const float*)d_in[12];
  const float* av = (const float*)d_in[13];
  const float* uv = (const float*)d_in[14];

  char* ws = (char*)d_ws;
  u16* xb       = (u16*)(ws);                      // 16 MB  [0,16M)
  u16* attn_o   = (u16*)(ws);                      // 16 MB  (reuse: xb dead after QKV GEMM)
  u16* qkv      = (u16*)(ws + (16u << 20));        // 48 MB  [16M,64M)
  u16* weffT    = (u16*)(ws + (64u << 20));        // 8 MB   [64M,72M)
  float* biasq  = (float*)(ws + (72u << 20));      // 12 KB

  conv_x_kernel<<<dim3(8192), dim3(256), 0, stream>>>(x, xb);
  prep_w_kernel<<<dim3(1024, 4), dim3(256), 0, stream>>>(wq, wk, wv, wo, aq, ak, av, uq, uk, uv, weffT);
  prep_bias_kernel<<<dim3(12), dim3(256), 0, stream>>>(bq, bk, bv, biasq);
  gemm_tt<true><<<dim3(24, 64), dim3(256), 0, stream>>>(weffT, xb, (void*)qkv, biasq, 3072, 1024);
  attn_kernel<<<dim3(16, 16, 4), dim3(256), 0, stream>>>(qkv, attn_o);
  gemm_tt<false><<<dim3(8, 64), dim3(256), 0, stream>>>(weffT + 3u * 1048576u, attn_o, d_out, bo, 1024, 1024);
}

// Round 3
// 301.868 us; speedup vs baseline: 1.3270x; 1.1938x over previous
//
#include <hip/hip_runtime.h>
#include <stdint.h>

typedef unsigned short u16;
typedef unsigned int u32;
typedef __bf16 bf16x8 __attribute__((ext_vector_type(8)));
typedef __bf16 bf16x4 __attribute__((ext_vector_type(4)));
typedef float f32x4 __attribute__((ext_vector_type(4)));

#define SEQ 2048
#define QSCALE 0.1803368801111137f  // log2(e)/8, folded into W_q_eff

__device__ __forceinline__ float fast_exp2(float x) {
#if __has_builtin(__builtin_amdgcn_exp2f)
  return __builtin_amdgcn_exp2f(x);
#else
  return exp2f(x);
#endif
}

// async 16B global->LDS copy (wave-uniform LDS base + lane*16)
__device__ __forceinline__ void async16(const void* g, void* l) {
  __builtin_amdgcn_global_load_lds((const __attribute__((address_space(1))) void*)g,
                                   (__attribute__((address_space(3))) void*)l, 16, 0, 0);
}

// ---------------- prep kernels ----------------

__global__ void conv_x_kernel(const float* __restrict__ x, u16* __restrict__ xb) {
  int i = (blockIdx.x * 256 + threadIdx.x) * 4;
  float4 v = *(const float4*)(x + i);
  bf16x4 o;
  o[0] = (__bf16)v.x; o[1] = (__bf16)v.y; o[2] = (__bf16)v.z; o[3] = (__bf16)v.w;
  *(bf16x4*)(xb + i) = o;
}

// WeffT[p][n][k] = w_p[k][n] + 2*sum_r a_p[k][r]*u_p[r][n]; p==0 scaled by QSCALE
__global__ void prep_w_kernel(const float* __restrict__ wq, const float* __restrict__ wk,
                              const float* __restrict__ wv, const float* __restrict__ wo,
                              const float* __restrict__ aq, const float* __restrict__ ak,
                              const float* __restrict__ av,
                              const float* __restrict__ uq, const float* __restrict__ uk,
                              const float* __restrict__ uv,
                              u16* __restrict__ weffT) {
  const int p = blockIdx.y;
  const int tn0 = (blockIdx.x & 31) * 32, tk0 = (blockIdx.x >> 5) * 32;
  const float* w = (p == 0) ? wq : (p == 1) ? wk : (p == 2) ? wv : wo;
  const float* a = (p == 0) ? aq : (p == 1) ? ak : av;
  const float* u = (p == 0) ? uq : (p == 1) ? uk : uv;
  __shared__ float wt[32][33];
  __shared__ float at[32][8];
  __shared__ float ut[8][33];
  const int t = threadIdx.x;
  {
    int tk = t >> 3, tn4 = (t & 7) * 4;
    float4 v = *(const float4*)(w + (tk0 + tk) * 1024 + tn0 + tn4);
    wt[tk][tn4] = v.x; wt[tk][tn4 + 1] = v.y; wt[tk][tn4 + 2] = v.z; wt[tk][tn4 + 3] = v.w;
  }
  if (p < 3) {
    at[t >> 3][t & 7] = a[(tk0 + (t >> 3)) * 8 + (t & 7)];
    ut[t >> 5][t & 31] = u[(t >> 5) * 1024 + tn0 + (t & 31)];
  }
  __syncthreads();
  const int tn = t >> 3, tk4 = (t & 7) * 4;
  bf16x4 o;
#pragma unroll
  for (int jj = 0; jj < 4; ++jj) {
    int k = tk4 + jj;
    float val = wt[k][tn];
    if (p < 3) {
      float acc = 0.f;
#pragma unroll
      for (int r = 0; r < 8; ++r) acc += at[k][r] * ut[r][tn];
      val += 2.0f * acc;
    }
    if (p == 0) val *= QSCALE;
    o[jj] = (__bf16)val;
  }
  *(bf16x4*)(weffT + p * 1048576 + (tn0 + tn) * 1024 + tk0 + tk4) = o;
}

__global__ void prep_bias_kernel(const float* __restrict__ bq, const float* __restrict__ bk,
                                 const float* __restrict__ bv, float* __restrict__ bias_qkv) {
  int i = blockIdx.x * 256 + threadIdx.x;
  bias_qkv[i] = (i < 1024) ? bq[i] * QSCALE : (i < 2048) ? bk[i - 1024] : bv[i - 2048];
}

// ---------------- GEMM: OUT[v][u] = dot(U[u], V[v]) + bias[u] ----------------
// Block 128(u) x 128(v), BK=32, 4 waves 2x2, wave tile 64x64 (4x4 MFMAs).
// MODE 0: fp32 dense store (stride NU). MODE 1: u<2048 -> bf16 qkv (stride 2048);
//         u>=2048 -> V^T scatter into vT[b][h][d][s] (L2 merges to full lines).

template <int MODE>
__global__ __launch_bounds__(256, 2)
void gemm_tt(const u16* __restrict__ U, const u16* __restrict__ V, void* __restrict__ OUT,
             u16* __restrict__ vT, const float* __restrict__ bias, const int NU, const int K) {
  __shared__ __align__(16) char smU[8192];
  __shared__ __align__(16) char smV[8192];
  const int t = threadIdx.x;
  const int lane = t & 63, ln = lane & 15, g = lane >> 4, w = t >> 6;
  const int u0 = blockIdx.x * 128, v0 = blockIdx.y * 128;
  const int wu = (w & 1) * 64, wv = (w >> 1) * 64;
  f32x4 acc[4][4] = {};
  for (int k0 = 0; k0 < K; k0 += 32) {
    __syncthreads();
#pragma unroll
    for (int half = 0; half < 2; ++half) {
      int p = half * 256 + t;
      int s = p >> 2, cp = p & 3;
      int c = cp ^ (s & 3);
      int ldsoff = (half * 256 + (t & 192)) * 16;
      async16(U + (u0 + s) * K + k0 + c * 8, smU + ldsoff);
      async16(V + (v0 + s) * K + k0 + c * 8, smV + ldsoff);
    }
    __syncthreads();
    bf16x8 af[4], bf[4];
#pragma unroll
    for (int mt = 0; mt < 4; ++mt)
      af[mt] = *(const bf16x8*)(smU + (wu + mt * 16 + ln) * 64 + ((g ^ (ln & 3)) * 16));
#pragma unroll
    for (int nt = 0; nt < 4; ++nt)
      bf[nt] = *(const bf16x8*)(smV + (wv + nt * 16 + ln) * 64 + ((g ^ (ln & 3)) * 16));
#pragma unroll
    for (int mt = 0; mt < 4; ++mt)
#pragma unroll
      for (int nt = 0; nt < 4; ++nt)
        acc[mt][nt] = __builtin_amdgcn_mfma_f32_16x16x32_bf16(af[mt], bf[nt], acc[mt][nt], 0, 0, 0);
  }
  const bool isV = (MODE == 1) && (u0 + wu >= 2048);  // wave-uniform
#pragma unroll
  for (int mt = 0; mt < 4; ++mt) {
    const int u = u0 + wu + mt * 16 + g * 4;
    const float4 bs = *(const float4*)(bias + u);
#pragma unroll
    for (int nt = 0; nt < 4; ++nt) {
      const int v = v0 + wv + nt * 16 + ln;
      f32x4 a = acc[mt][nt];
      a[0] += bs.x; a[1] += bs.y; a[2] += bs.z; a[3] += bs.w;
      if (MODE == 0) {
        *(float4*)((float*)OUT + (size_t)v * NU + u) = make_float4(a[0], a[1], a[2], a[3]);
      } else if (!isV) {
        bf16x4 o;
        o[0] = (__bf16)a[0]; o[1] = (__bf16)a[1]; o[2] = (__bf16)a[2]; o[3] = (__bf16)a[3];
        *(bf16x4*)((u16*)OUT + (size_t)v * 2048 + u) = o;
      } else {
        const int uu = u - 2048;
        const int hh = uu >> 6, dd = uu & 63;
        const int bb = v >> 11, ss = v & 2047;
        u16* dst = vT + ((size_t)((bb * 16 + hh) * 64 + dd)) * 2048 + ss;
#pragma unroll
        for (int r = 0; r < 4; ++r)
          *(__bf16*)(dst + (size_t)r * 2048) = (__bf16)a[r];
      }
    }
  }
}

// ---------------- flash attention v3 ----------------
// Block = (h, qt, b), 128 q, 4 waves x 32 q. Q frags in registers. Fixed-max
// softmax (m=0; scores pre-scaled by log2e/8 in W_q): P = exp2(raw S).
// l computed by MFMA via ones-row appended to V^T (rows 64..79 of smVt).
// smK  [128 s'][128B, 8 chunks swz ^(r&7)]            (async16)
// smVt [80 d][256B, 16 chunks swz ^((d&15)^(d>>3))]   (async16 from global vT)
// smP  per wave [32 q][64B, 4 chunks swz ^((q>>2)&3)] (wave-private)

__global__ __launch_bounds__(256, 2)
void attn_kernel(const u16* __restrict__ qkv, const u16* __restrict__ vT,
                 u16* __restrict__ attn_o) {
  __shared__ __align__(16) char smK[16384];
  __shared__ __align__(16) char smVt[20480];
  __shared__ __align__(16) char smP[8192];
  const int t = threadIdx.x;
  const int lane = t & 63, ln = lane & 15, g = lane >> 4, w = t >> 6;
  const int h = blockIdx.x, qt = blockIdx.y, b = blockIdx.z;
  const int q0 = qt * 128;
  const size_t base_b = (size_t)b * SEQ * 2048;
  const u16* qbase = qkv + base_b + h * 64;
  const u16* kbase0 = qkv + base_b + 1024 + h * 64;
  const u16* vbase0 = vT + ((size_t)(b * 16 + h) * 64) * 2048;

  // ones-row block: row 64 = 1.0, rows 65..79 = 0 (constant rows: swizzle-proof)
  {
    u32 val = ((t >> 4) == 0) ? 0x3F803F80u : 0u;
    uint4 q4 = {val, val, val, val};
    *(uint4*)(smVt + 16384 + t * 16) = q4;
  }

  // Q fragments in registers: (kk, nt): q = q0 + w*32 + nt*16 + ln, k = kk*32 + g*8
  bf16x8 qf[2][2];
#pragma unroll
  for (int kk = 0; kk < 2; ++kk)
#pragma unroll
    for (int nt = 0; nt < 2; ++nt)
      qf[kk][nt] = *(const bf16x8*)(qbase + (size_t)(q0 + w * 32 + nt * 16 + ln) * 2048 +
                                    kk * 32 + g * 8);

  // per-thread staging pointers (swizzled source, advance per kt)
  const u16* srcK[4];
  const u16* srcV[4];
  char* dstK[4];
  char* dstV[4];
#pragma unroll
  for (int i = 0; i < 4; ++i) {
    int p = i * 256 + t;
    {
      int row = p >> 3, cp = p & 7, c = cp ^ (row & 7);
      srcK[i] = kbase0 + (size_t)row * 2048 + c * 8;
      dstK[i] = smK + (i * 256 + (t & 192)) * 16;
    }
    {
      int d = p >> 4, cp = p & 15;
      int key = (d & 15) ^ (d >> 3);
      int c = (cp ^ key) & 15;
      srcV[i] = vbase0 + (size_t)d * 2048 + c * 8;
      dstV[i] = smVt + (i * 256 + (t & 192)) * 16;
    }
  }

  f32x4 accO[5][2] = {};

  for (int kt = 0; kt < 16; ++kt) {
    __syncthreads();  // prev iter (and pre-loop ones-write) done with LDS
#pragma unroll
    for (int i = 0; i < 4; ++i) {
      async16(srcK[i], dstK[i]);
      srcK[i] += 128 * 2048;
    }
#pragma unroll
    for (int i = 0; i < 4; ++i) {
      async16(srcV[i], dstV[i]);
      srcV[i] += 128;
    }
    __syncthreads();
    // S^T = K @ Q^T : rows s' (8 m-tiles), cols = wave's 32 q (2 n-tiles)
    f32x4 st[8][2] = {};
#pragma unroll
    for (int kk = 0; kk < 2; ++kk) {
#pragma unroll
      for (int mt = 0; mt < 8; ++mt) {
        int row = mt * 16 + ln;
        bf16x8 kf = *(const bf16x8*)(smK + row * 128 + (((4 * kk + g) ^ (ln & 7)) * 16));
        st[mt][0] = __builtin_amdgcn_mfma_f32_16x16x32_bf16(kf, qf[kk][0], st[mt][0], 0, 0, 0);
        st[mt][1] = __builtin_amdgcn_mfma_f32_16x16x32_bf16(kf, qf[kk][1], st[mt][1], 0, 0, 0);
      }
    }
    // P = exp2(S) (no max, no rescale), pack to smP, PV per 32-s' chunk
    char* pw = smP + w * 2048;
#pragma unroll
    for (int kk = 0; kk < 4; ++kk) {
#pragma unroll
      for (int mt2 = 0; mt2 < 2; ++mt2)
#pragma unroll
        for (int nt = 0; nt < 2; ++nt) {
          f32x4 sv = st[kk * 2 + mt2][nt];
          bf16x4 pk;
#pragma unroll
          for (int r = 0; r < 4; ++r) pk[r] = (__bf16)fast_exp2(sv[r]);
          int q = nt * 16 + ln;
          int c = 2 * mt2 + (g >> 1);
          *(bf16x4*)(pw + q * 64 + (((c ^ ((q >> 2) & 3)) & 3) * 16) + (g & 1) * 8) = pk;
        }
      int keyr = (ln >> 2) & 3;
      bf16x8 pf0 = *(const bf16x8*)(pw + ln * 64 + (((g ^ keyr) & 3) * 16));
      bf16x8 pf1 = *(const bf16x8*)(pw + (16 + ln) * 64 + (((g ^ keyr) & 3) * 16));
#pragma unroll
      for (int ot = 0; ot < 5; ++ot) {
        int row = ot * 16 + ln;
        int key = (row & 15) ^ (row >> 3);
        bf16x8 vf = *(const bf16x8*)(smVt + row * 256 + (((4 * kk + g) ^ key) & 15) * 16);
        accO[ot][0] = __builtin_amdgcn_mfma_f32_16x16x32_bf16(vf, pf0, accO[ot][0], 0, 0, 0);
        accO[ot][1] = __builtin_amdgcn_mfma_f32_16x16x32_bf16(vf, pf1, accO[ot][1], 0, 0, 0);
      }
    }
  }
  // epilogue: l lives in C-row 64 = lane(ln, g=0) reg0 of accO[4]; broadcast via shfl
#pragma unroll
  for (int nt = 0; nt < 2; ++nt) {
    float lv = __shfl(accO[4][nt][0], ln);
    float il = 1.0f / lv;
    const int s = q0 + w * 32 + nt * 16 + ln;
#pragma unroll
    for (int ot = 0; ot < 4; ++ot) {
      bf16x4 o;
#pragma unroll
      for (int r = 0; r < 4; ++r) o[r] = (__bf16)(accO[ot][nt][r] * il);
      *(bf16x4*)(attn_o + (size_t)(b * SEQ + s) * 1024 + h * 64 + ot * 16 + g * 4) = o;
    }
  }
}

// ---------------- launcher ----------------

extern "C" void kernel_launch(void* const* d_in, const int* in_sizes, int n_in,
                              void* d_out, int out_size, void* d_ws, size_t ws_size,
                              hipStream_t stream) {
  const float* x  = (const float*)d_in[0];
  const float* wq = (const float*)d_in[1];
  const float* bq = (const float*)d_in[2];
  const float* wk = (const float*)d_in[3];
  const float* bk = (const float*)d_in[4];
  const float* wv = (const float*)d_in[5];
  const float* bv = (const float*)d_in[6];
  const float* wo = (const float*)d_in[7];
  const float* bo = (const float*)d_in[8];
  const float* aq = (const float*)d_in[9];
  const float* uq = (const float*)d_in[10];
  const float* ak = (const float*)d_in[11];
  const float* uk = (const float*)d_in[12];
  const float* av = (const float*)d_in[13];
  const float* uv = (const float*)d_in[14];

  char* ws = (char*)d_ws;
  u16* xb       = (u16*)(ws);                      // 16 MB [0,16M)  (dead after QKV GEMM)
  u16* attn_o   = (u16*)(ws);                      // 16 MB (reuse)
  u16* qkv      = (u16*)(ws + (16u << 20));        // 32 MB [16M,48M)  Q,K stride 2048
  u16* vT       = (u16*)(ws + (48u << 20));        // 16 MB [48M,64M)  [b][h][d][s]
  u16* weffT    = (u16*)(ws + (64u << 20));        // 8 MB  [64M,72M)
  float* biasq  = (float*)(ws + (72u << 20));      // 12 KB

  conv_x_kernel<<<dim3(8192), dim3(256), 0, stream>>>(x, xb);
  prep_w_kernel<<<dim3(1024, 4), dim3(256), 0, stream>>>(wq, wk, wv, wo, aq, ak, av, uq, uk, uv, weffT);
  prep_bias_kernel<<<dim3(12), dim3(256), 0, stream>>>(bq, bk, bv, biasq);
  gemm_tt<1><<<dim3(24, 64), dim3(256), 0, stream>>>(weffT, xb, (void*)qkv, vT, biasq, 2048, 1024);
  attn_kernel<<<dim3(16, 16, 4), dim3(256), 0, stream>>>(qkv, vT, attn_o);
  gemm_tt<0><<<dim3(8, 64), dim3(256), 0, stream>>>(weffT + 3u * 1048576u, attn_o, d_out, nullptr, bo, 1024, 1024);
}